// Round 13
// baseline (217.813 us; speedup 1.0000x reference)
//
#include <hip/hip_runtime.h>
#include <math.h>

// LorentzNotGroupNorm, MI355X. x:(64,3136,128) fp32, groups=8.
// Group = 8 consecutive pixels x 128 ch = 4KB.
// Structure = R12 (best passing: 200.9us) with finalize FOLDED AWAY:
//   - pass1's q==0 lanes atomicAdd nvar directly into var_sum[b*8+p]
//     (device-scope by default; consumer is a SEPARATE dispatch -> kernel
//     boundary guarantees visibility; no G16 in-kernel hazard).
//   - var_sum zeroed via hipMemsetAsync on the stream (capture-safe).
//   - pass2 computes <beta,beta>_L locally per wave (5-shuffle butterfly)
//     and reads var = var_sum*(1/392).
// Only numeric delta vs R12: var summation order (atomic, unordered),
// perturbation ~2e-6 relative << 2^-7 tolerance.
//   pe = sc^2*Gyy + k^2*Gaa + 2sc*k*Gya + g0^2*coef*(coef+2*T0)
//   pb = sc*By + k*Ba - b0g0*(2*T0+coef)
//   na = sc^2*yy + k^2*aa + 2sc*k*ya + coef^2 + 2*coef*T0

constexpr int S_GROUPS = 392;              // spatial groups per batch
constexpr int N_GROUPS = 64 * S_GROUPS;    // 25088
constexpr int CSTRIDE = 64;                // floats/group: 8 pixels x 8

__device__ __forceinline__ void wave_lds_fence() {
  __asm__ volatile("" ::: "memory");
  __builtin_amdgcn_wave_barrier();
  __asm__ volatile("" ::: "memory");
}

// Pixel-mean fold over lane bits {32,16,8}; lane (p,q) ends with mean
// channels {16q+2p, 16q+2p+1} in (c0,c1).
__device__ __forceinline__ void fold_mean(const float v[16], int lane,
                                          float& c0, float& c1) {
  float a8[8];
  const bool h5 = (lane & 32) != 0;
#pragma unroll
  for (int i = 0; i < 8; ++i) {
    float kp = h5 ? v[i + 8] : v[i];
    float sd = h5 ? v[i] : v[i + 8];
    a8[i] = kp + __shfl_xor(sd, 32, 64);
  }
  float a4[4];
  const bool h4 = (lane & 16) != 0;
#pragma unroll
  for (int i = 0; i < 4; ++i) {
    float kp = h4 ? a8[i + 4] : a8[i];
    float sd = h4 ? a8[i] : a8[i + 4];
    a4[i] = kp + __shfl_xor(sd, 16, 64);
  }
  const bool h3 = (lane & 8) != 0;
  float kp0 = h3 ? a4[2] : a4[0], sd0 = h3 ? a4[0] : a4[2];
  float kp1 = h3 ? a4[3] : a4[1], sd1 = h3 ? a4[1] : a4[3];
  c0 = (kp0 + __shfl_xor(sd0, 8, 64)) * 0.125f;
  c1 = (kp1 + __shfl_xor(sd1, 8, 64)) * 0.125f;
}

__global__ __launch_bounds__(256) void lngn_pass1(
    const float* __restrict__ x, const float* __restrict__ gamma,
    const float* __restrict__ beta, float* var_sum,
    float* __restrict__ cache) {
  __shared__ float sm[4][128];
  const int w = threadIdx.x >> 6, lane = threadIdx.x & 63;
  const int p = lane >> 3, q = lane & 7;
  const int wid = blockIdx.x * 4 + w;        // ONE group per wave
  const float* b0 = x + (size_t)wid * 1024 + p * 128 + q * 16;
  float* gc = cache + (size_t)wid * CSTRIDE;

  float v[16], gm[16], bt[16];
#pragma unroll
  for (int j = 0; j < 4; ++j) {
    *reinterpret_cast<float4*>(&v[4 * j]) =
        *reinterpret_cast<const float4*>(b0 + 4 * j);
    *reinterpret_cast<float4*>(&gm[4 * j]) =
        *reinterpret_cast<const float4*>(gamma + q * 16 + 4 * j);
    *reinterpret_cast<float4*>(&bt[4 * j]) =
        *reinterpret_cast<const float4*>(beta + q * 16 + 4 * j);
  }

  // fold -> LDS
  float c0, c1;
  fold_mean(v, lane, c0, c1);
  *reinterpret_cast<float2*>(&sm[w][q * 16 + p * 2]) = make_float2(c0, c1);
  wave_lds_fence();
  float avg[16];
#pragma unroll
  for (int j = 0; j < 4; ++j)
    *reinterpret_cast<float4*>(&avg[4 * j]) =
        *reinterpret_cast<const float4*>(&sm[w][q * 16 + 4 * j]);

  // fused dot loop: 8 Euclid accumulators
  float pa = 0.f, pd = 0.f, py = 0.f;
  float Gyy = 0.f, Gya = 0.f, Gaa = 0.f, By = 0.f, Ba = 0.f;
#pragma unroll
  for (int i = 0; i < 16; ++i) {
    const float gy = gm[i] * v[i], ga = gm[i] * avg[i];
    pa = fmaf(avg[i], avg[i], pa);
    pd = fmaf(avg[i], v[i], pd);
    py = fmaf(v[i], v[i], py);
    Gyy = fmaf(gy, gy, Gyy);
    Gya = fmaf(gy, ga, Gya);
    Gaa = fmaf(ga, ga, Gaa);
    By = fmaf(bt[i], gy, By);
    Ba = fmaf(bt[i], ga, Ba);
  }
  // one rsum round: 8 values x 3 stages over q-bits {1,2,4}
#pragma unroll
  for (int m = 1; m <= 4; m <<= 1) {
    pa += __shfl_xor(pa, m, 64);
    pd += __shfl_xor(pd, m, 64);
    py += __shfl_xor(py, m, 64);
    Gyy += __shfl_xor(Gyy, m, 64);
    Gya += __shfl_xor(Gya, m, 64);
    Gaa += __shfl_xor(Gaa, m, 64);
    By += __shfl_xor(By, m, 64);
    Ba += __shfl_xor(Ba, m, 64);
  }
  const float y0 = __shfl(v[0], lane & 56, 64);   // y_p[0]
  const float avg0 = __shfl(avg[0], 0, 64);       // avg channel 0
  const float gm0 = gamma[0], b0g0 = beta[0] * gamma[0];

  // scalar chain -- fast HW transcendentals (<=~1ulp; tolerance 2^-7)
  const float aaL = pa - 2.f * avg0 * avg0;
  const float rden = rsqrtf(fmaxf(-aaL, 1e-8f));
  const float mean0 = rden * avg0;
  const float yaL = pd - 2.f * avg0 * y0;
  const float yyL = py - 2.f * y0 * y0;
  const float a_raw = -yaL * rden;
  const float alpha = fmaxf(a_raw, 1.f + 1e-7f);
  const float t = alpha - 1.f;
  const float dist = __logf(alpha + sqrtf(t * (alpha + 1.f)));  // arccosh
  const float inn = fmaxf(yyL + 2.f * alpha * a_raw - alpha * alpha, 1e-8f);
  const float sc = dist * rsqrtf(inn);
  const float am = alpha * rden;
  const float v0 = sc * (y0 - am * avg0);
  const float coef = __fdividef(-v0, 1.f + mean0);
  const float k = coef * rden - sc * am;
  const float T0 = fmaf(sc, y0, k * avg0);
  const float na = sc * sc * py + k * k * pa + 2.f * sc * k * pd +
                   coef * coef + 2.f * coef * T0;
  const float nvar = sqrtf(fmaxf(na, 0.f));
  const float pe = sc * sc * Gyy + k * k * Gaa + 2.f * sc * k * Gya +
                   gm0 * gm0 * coef * (coef + 2.f * T0);
  const float pb = fmaf(sc, By, k * Ba) - b0g0 * (2.f * T0 + coef);
  const float XT0 = T0 + coef;

  if (q == 0) {
    *reinterpret_cast<float4*>(gc + p * 8) = make_float4(sc, k, coef, pe);
    *reinterpret_cast<float4*>(gc + p * 8 + 4) =
        make_float4(pb, XT0, 0.f, 0.f);
    const int b = wid / S_GROUPS;
    atomicAdd(&var_sum[b * 8 + p], nvar);   // device-scope; read next dispatch
  }
}

__global__ __launch_bounds__(256) void lngn_pass2(
    const float* __restrict__ x, const float* __restrict__ gamma,
    const float* __restrict__ beta, const float* __restrict__ var_sum,
    const float* __restrict__ cache, float* __restrict__ out) {
  const int w = threadIdx.x >> 6, lane = threadIdx.x & 63;
  const int wid = blockIdx.x * 4 + w;
  const float* xb = x + (size_t)wid * 1024;
  const float* gc = cache + (size_t)wid * CSTRIDE;
  const int cl = lane & 31;   // channel-quad index: channels 4*cl..+3
  const int par = lane >> 5;  // pixel parity

  // wave-contiguous loads: instruction j covers bytes [j*1024 + lane*16)
  float4 xv[4];
#pragma unroll
  for (int j = 0; j < 4; ++j)
    xv[j] = *reinterpret_cast<const float4*>(xb + j * 256 + 4 * lane);
  const float4 gm4 = *reinterpret_cast<const float4*>(gamma + 4 * cl);
  const float4 bt4 = *reinterpret_cast<const float4*>(beta + 4 * cl);

  // recompute group mean locally (R12-verified): own 4 pixels + partner parity
  float4 sum;
  sum.x = xv[0].x + xv[1].x + xv[2].x + xv[3].x;
  sum.y = xv[0].y + xv[1].y + xv[2].y + xv[3].y;
  sum.z = xv[0].z + xv[1].z + xv[2].z + xv[3].z;
  sum.w = xv[0].w + xv[1].w + xv[2].w + xv[3].w;
  float4 av;
  av.x = (sum.x + __shfl_xor(sum.x, 32, 64)) * 0.125f;
  av.y = (sum.y + __shfl_xor(sum.y, 32, 64)) * 0.125f;
  av.z = (sum.z + __shfl_xor(sum.z, 32, 64)) * 0.125f;
  av.w = (sum.w + __shfl_xor(sum.w, 32, 64)) * 0.125f;

  // <beta,beta>_L computed locally per wave (R11-arithmetic, sound)
  const float bt0 = beta[0], gm0 = gamma[0];
  float pbbE = bt4.x * bt4.x + bt4.y * bt4.y + bt4.z * bt4.z + bt4.w * bt4.w;
#pragma unroll
  for (int m = 1; m <= 16; m <<= 1) pbbE += __shfl_xor(pbbE, m, 64);
  const float pbb = pbbE - 2.f * bt0 * bt0;

  // per-pixel A-chain (lane computes pixel lane&7; 8-fold redundant)
  const int pix = lane & 7;
  const float4 s0 = *reinterpret_cast<const float4*>(gc + pix * 8);
  const float4 s1v = *reinterpret_cast<const float4*>(gc + pix * 8 + 4);
  const float sc = s0.x, kk = s0.y, coef = s0.z, PE = s0.w;
  const float PB = s1v.x, XT0 = s1v.y;
  const int b = wid / S_GROUPS;
  const float varv = var_sum[b * 8 + pix] * (1.f / (float)S_GROUPS);

  const float is1 = __fdividef(1.f, varv + 1e-5f);
  const float pe = is1 * is1 * PE;
  const float pb = is1 * PB;
  const float u0 = is1 * gm0 * XT0;
  const float n = sqrtf(pe);
  const float scl = fminf(1.f, __fdividef(10.f, fmaxf(n, 1e-8f)));
  const float c2 = scl * pb * __fdividef(1.f, 1.f + bt0);
  const float uuL = pe - 2.f * u0 * u0;
  const float innw = scl * scl * uuL + 2.f * scl * c2 * (pb - u0) +
                     c2 * c2 * (pbb - 2.f * bt0 - 1.f);
  const float nrm = sqrtf(fmaxf(innw, 1e-8f));
  const float e = __expf(nrm);
  const float ie = __fdividef(1.f, e);
  const float chv = 0.5f * (e + ie);
  const float isn = __fdividef(0.5f * (e - ie), nrm);
  const float A1 = chv + isn * c2;        // * beta_i
  const float Cu = isn * scl * is1;
  const float A2 = Cu * sc;               // * gamma_i * x_i
  const float A3 = Cu * kk;               // * gamma_i * avg_i
  const float A4 = fmaf(Cu * gm0, coef, isn * c2);  // += at channel 0

  float* ob = out + (size_t)wid * 1024;
#pragma unroll
  for (int j = 0; j < 4; ++j) {
    const int sp = 2 * j + par;           // pixel of this lane's j-th quad
    const float a1 = __shfl(A1, sp, 64);
    const float a2 = __shfl(A2, sp, 64);
    const float a3 = __shfl(A3, sp, 64);
    const float a4 = __shfl(A4, sp, 64);
    float4 o4;
    o4.x = fmaf(a1, bt4.x, gm4.x * fmaf(a2, xv[j].x, a3 * av.x));
    o4.y = fmaf(a1, bt4.y, gm4.y * fmaf(a2, xv[j].y, a3 * av.y));
    o4.z = fmaf(a1, bt4.z, gm4.z * fmaf(a2, xv[j].z, a3 * av.z));
    o4.w = fmaf(a1, bt4.w, gm4.w * fmaf(a2, xv[j].w, a3 * av.w));
    if (cl == 0) o4.x += a4;              // channel 0 of this pixel
    *reinterpret_cast<float4*>(ob + j * 256 + 4 * lane) = o4;
  }
}

extern "C" void kernel_launch(void* const* d_in, const int* in_sizes, int n_in,
                              void* d_out, int out_size, void* d_ws,
                              size_t ws_size, hipStream_t stream) {
  const float* x = (const float*)d_in[0];
  const float* gamma = (const float*)d_in[1];
  const float* beta = (const float*)d_in[2];
  float* out = (float*)d_out;
  float* var_sum = (float*)d_ws;           // 512 floats (atomic accumulators)
  float* cache = var_sum + 512;            // 16B-aligned, ~6.4 MB

  hipMemsetAsync(var_sum, 0, 512 * sizeof(float), stream);
  lngn_pass1<<<N_GROUPS / 4, 256, 0, stream>>>(x, gamma, beta, var_sum, cache);
  lngn_pass2<<<N_GROUPS / 4, 256, 0, stream>>>(x, gamma, beta, var_sum, cache,
                                               out);
}

// Round 14
// 200.778 us; speedup vs baseline: 1.0848x; 1.0848x over previous
//
#include <hip/hip_runtime.h>
#include <math.h>

// LorentzNotGroupNorm, MI355X. x:(64,3136,128) fp32, groups=8.
// Group = 8 consecutive pixels x 128 ch = 4KB.
// Structure = R12 (best passing: 200.9us), reverted verbatim after R13's
// atomic experiment regressed (+26us on pass1: 200k device-scope atomicAdds
// onto 64 hot 32B lines serialize cross-XCD -- Guideline 12 validated).
// pass1 caches ONLY the per-pixel bundle {sc,k,coef,PE,PB,XT0} (CSTRIDE=64);
// pass2 recomputes the group mean locally (channel-major, 4-pixel sum +
// xor32 shuffle); finalize kernel does the var mean + <beta,beta>_L.
//   pe = sc^2*Gyy + k^2*Gaa + 2sc*k*Gya + g0^2*coef*(coef+2*T0)
//   pb = sc*By + k*Ba - b0g0*(2*T0+coef)
//   na = sc^2*yy + k^2*aa + 2sc*k*ya + coef^2 + 2*coef*T0

constexpr int S_GROUPS = 392;              // spatial groups per batch
constexpr int N_GROUPS = 64 * S_GROUPS;    // 25088
constexpr int CSTRIDE = 64;                // floats/group: 8 pixels x 8

__device__ __forceinline__ void wave_lds_fence() {
  __asm__ volatile("" ::: "memory");
  __builtin_amdgcn_wave_barrier();
  __asm__ volatile("" ::: "memory");
}

// Pixel-mean fold over lane bits {32,16,8}; lane (p,q) ends with mean
// channels {16q+2p, 16q+2p+1} in (c0,c1).
__device__ __forceinline__ void fold_mean(const float v[16], int lane,
                                          float& c0, float& c1) {
  float a8[8];
  const bool h5 = (lane & 32) != 0;
#pragma unroll
  for (int i = 0; i < 8; ++i) {
    float kp = h5 ? v[i + 8] : v[i];
    float sd = h5 ? v[i] : v[i + 8];
    a8[i] = kp + __shfl_xor(sd, 32, 64);
  }
  float a4[4];
  const bool h4 = (lane & 16) != 0;
#pragma unroll
  for (int i = 0; i < 4; ++i) {
    float kp = h4 ? a8[i + 4] : a8[i];
    float sd = h4 ? a8[i] : a8[i + 4];
    a4[i] = kp + __shfl_xor(sd, 16, 64);
  }
  const bool h3 = (lane & 8) != 0;
  float kp0 = h3 ? a4[2] : a4[0], sd0 = h3 ? a4[0] : a4[2];
  float kp1 = h3 ? a4[3] : a4[1], sd1 = h3 ? a4[1] : a4[3];
  c0 = (kp0 + __shfl_xor(sd0, 8, 64)) * 0.125f;
  c1 = (kp1 + __shfl_xor(sd1, 8, 64)) * 0.125f;
}

__global__ __launch_bounds__(256) void lngn_pass1(
    const float* __restrict__ x, const float* __restrict__ gamma,
    const float* __restrict__ beta, float* __restrict__ var_part,
    float* __restrict__ cache) {
  __shared__ float sm[4][128];
  const int w = threadIdx.x >> 6, lane = threadIdx.x & 63;
  const int p = lane >> 3, q = lane & 7;
  const int wid = blockIdx.x * 4 + w;        // ONE group per wave
  const float* b0 = x + (size_t)wid * 1024 + p * 128 + q * 16;
  float* gc = cache + (size_t)wid * CSTRIDE;

  float v[16], gm[16], bt[16];
#pragma unroll
  for (int j = 0; j < 4; ++j) {
    *reinterpret_cast<float4*>(&v[4 * j]) =
        *reinterpret_cast<const float4*>(b0 + 4 * j);
    *reinterpret_cast<float4*>(&gm[4 * j]) =
        *reinterpret_cast<const float4*>(gamma + q * 16 + 4 * j);
    *reinterpret_cast<float4*>(&bt[4 * j]) =
        *reinterpret_cast<const float4*>(beta + q * 16 + 4 * j);
  }

  // fold -> LDS
  float c0, c1;
  fold_mean(v, lane, c0, c1);
  *reinterpret_cast<float2*>(&sm[w][q * 16 + p * 2]) = make_float2(c0, c1);
  wave_lds_fence();
  float avg[16];
#pragma unroll
  for (int j = 0; j < 4; ++j)
    *reinterpret_cast<float4*>(&avg[4 * j]) =
        *reinterpret_cast<const float4*>(&sm[w][q * 16 + 4 * j]);

  // fused dot loop: 8 Euclid accumulators
  float pa = 0.f, pd = 0.f, py = 0.f;
  float Gyy = 0.f, Gya = 0.f, Gaa = 0.f, By = 0.f, Ba = 0.f;
#pragma unroll
  for (int i = 0; i < 16; ++i) {
    const float gy = gm[i] * v[i], ga = gm[i] * avg[i];
    pa = fmaf(avg[i], avg[i], pa);
    pd = fmaf(avg[i], v[i], pd);
    py = fmaf(v[i], v[i], py);
    Gyy = fmaf(gy, gy, Gyy);
    Gya = fmaf(gy, ga, Gya);
    Gaa = fmaf(ga, ga, Gaa);
    By = fmaf(bt[i], gy, By);
    Ba = fmaf(bt[i], ga, Ba);
  }
  // one rsum round: 8 values x 3 stages over q-bits {1,2,4}
#pragma unroll
  for (int m = 1; m <= 4; m <<= 1) {
    pa += __shfl_xor(pa, m, 64);
    pd += __shfl_xor(pd, m, 64);
    py += __shfl_xor(py, m, 64);
    Gyy += __shfl_xor(Gyy, m, 64);
    Gya += __shfl_xor(Gya, m, 64);
    Gaa += __shfl_xor(Gaa, m, 64);
    By += __shfl_xor(By, m, 64);
    Ba += __shfl_xor(Ba, m, 64);
  }
  const float y0 = __shfl(v[0], lane & 56, 64);   // y_p[0]
  const float avg0 = __shfl(avg[0], 0, 64);       // avg channel 0
  const float gm0 = gamma[0], b0g0 = beta[0] * gamma[0];

  // scalar chain -- fast HW transcendentals (<=~1ulp; tolerance 2^-7)
  const float aaL = pa - 2.f * avg0 * avg0;
  const float rden = rsqrtf(fmaxf(-aaL, 1e-8f));
  const float mean0 = rden * avg0;
  const float yaL = pd - 2.f * avg0 * y0;
  const float yyL = py - 2.f * y0 * y0;
  const float a_raw = -yaL * rden;
  const float alpha = fmaxf(a_raw, 1.f + 1e-7f);
  const float t = alpha - 1.f;
  const float dist = __logf(alpha + sqrtf(t * (alpha + 1.f)));  // arccosh
  const float inn = fmaxf(yyL + 2.f * alpha * a_raw - alpha * alpha, 1e-8f);
  const float sc = dist * rsqrtf(inn);
  const float am = alpha * rden;
  const float v0 = sc * (y0 - am * avg0);
  const float coef = __fdividef(-v0, 1.f + mean0);
  const float k = coef * rden - sc * am;
  const float T0 = fmaf(sc, y0, k * avg0);
  const float na = sc * sc * py + k * k * pa + 2.f * sc * k * pd +
                   coef * coef + 2.f * coef * T0;
  const float nvar = sqrtf(fmaxf(na, 0.f));
  const float pe = sc * sc * Gyy + k * k * Gaa + 2.f * sc * k * Gya +
                   gm0 * gm0 * coef * (coef + 2.f * T0);
  const float pb = fmaf(sc, By, k * Ba) - b0g0 * (2.f * T0 + coef);
  const float XT0 = T0 + coef;

  if (q == 0) {
    *reinterpret_cast<float4*>(gc + p * 8) = make_float4(sc, k, coef, pe);
    *reinterpret_cast<float4*>(gc + p * 8 + 4) =
        make_float4(pb, XT0, 0.f, 0.f);
    const int b = wid / S_GROUPS;
    const int s = wid - b * S_GROUPS;
    var_part[(size_t)(b * 8 + p) * S_GROUPS + s] = nvar;
  }
}

__global__ __launch_bounds__(256) void lngn_finalize(
    const float* __restrict__ var_part, const float* __restrict__ beta,
    float* __restrict__ var_out) {
  const int wv = (int)((blockIdx.x * 256 + threadIdx.x) >> 6);  // 0..511 = b*8+p
  const int lane = threadIdx.x & 63;
  const float* base = var_part + (size_t)wv * S_GROUPS;
  float s = 0.f;
  for (int s0 = lane; s0 < S_GROUPS; s0 += 64) s += base[s0];
#pragma unroll
  for (int m = 32; m >= 1; m >>= 1) s += __shfl_xor(s, m, 64);
  if (lane == 0) var_out[wv] = s * (1.f / (float)S_GROUPS);

  // one wave additionally computes the global scalar <beta,beta>_L
  if (blockIdx.x == 0 && threadIdx.x < 64) {
    const int l = threadIdx.x;
    float b0v = beta[2 * l], b1v = beta[2 * l + 1];
    float tsum = b0v * b0v + b1v * b1v;
    if (l == 0) tsum -= 2.f * b0v * b0v;
#pragma unroll
    for (int m = 32; m >= 1; m >>= 1) tsum += __shfl_xor(tsum, m, 64);
    if (l == 0) var_out[512] = tsum;
  }
}

__global__ __launch_bounds__(256) void lngn_pass2(
    const float* __restrict__ x, const float* __restrict__ gamma,
    const float* __restrict__ beta, const float* __restrict__ var,
    const float* __restrict__ cache, float* __restrict__ out) {
  const int w = threadIdx.x >> 6, lane = threadIdx.x & 63;
  const int wid = blockIdx.x * 4 + w;
  const float* xb = x + (size_t)wid * 1024;
  const float* gc = cache + (size_t)wid * CSTRIDE;
  const int cl = lane & 31;   // channel-quad index: channels 4*cl..+3
  const int par = lane >> 5;  // pixel parity

  // wave-contiguous loads: instruction j covers bytes [j*1024 + lane*16)
  float4 xv[4];
#pragma unroll
  for (int j = 0; j < 4; ++j)
    xv[j] = *reinterpret_cast<const float4*>(xb + j * 256 + 4 * lane);
  const float4 gm4 = *reinterpret_cast<const float4*>(gamma + 4 * cl);
  const float4 bt4 = *reinterpret_cast<const float4*>(beta + 4 * cl);

  // recompute group mean locally (R4-verified): own 4 pixels + partner parity
  float4 sum;
  sum.x = xv[0].x + xv[1].x + xv[2].x + xv[3].x;
  sum.y = xv[0].y + xv[1].y + xv[2].y + xv[3].y;
  sum.z = xv[0].z + xv[1].z + xv[2].z + xv[3].z;
  sum.w = xv[0].w + xv[1].w + xv[2].w + xv[3].w;
  float4 av;
  av.x = (sum.x + __shfl_xor(sum.x, 32, 64)) * 0.125f;
  av.y = (sum.y + __shfl_xor(sum.y, 32, 64)) * 0.125f;
  av.z = (sum.z + __shfl_xor(sum.z, 32, 64)) * 0.125f;
  av.w = (sum.w + __shfl_xor(sum.w, 32, 64)) * 0.125f;

  // per-pixel A-chain (lane computes pixel lane&7; 8-fold redundant)
  const int pix = lane & 7;
  const float4 s0 = *reinterpret_cast<const float4*>(gc + pix * 8);
  const float4 s1v = *reinterpret_cast<const float4*>(gc + pix * 8 + 4);
  const float sc = s0.x, kk = s0.y, coef = s0.z, PE = s0.w;
  const float PB = s1v.x, XT0 = s1v.y;
  const int b = wid / S_GROUPS;
  const float varv = var[b * 8 + pix];
  const float pbb = var[512];
  const float bt0 = beta[0], gm0 = gamma[0];

  const float is1 = __fdividef(1.f, varv + 1e-5f);
  const float pe = is1 * is1 * PE;
  const float pb = is1 * PB;
  const float u0 = is1 * gm0 * XT0;
  const float n = sqrtf(pe);
  const float scl = fminf(1.f, __fdividef(10.f, fmaxf(n, 1e-8f)));
  const float c2 = scl * pb * __fdividef(1.f, 1.f + bt0);
  const float uuL = pe - 2.f * u0 * u0;
  const float innw = scl * scl * uuL + 2.f * scl * c2 * (pb - u0) +
                     c2 * c2 * (pbb - 2.f * bt0 - 1.f);
  const float nrm = sqrtf(fmaxf(innw, 1e-8f));
  const float e = __expf(nrm);
  const float ie = __fdividef(1.f, e);
  const float chv = 0.5f * (e + ie);
  const float isn = __fdividef(0.5f * (e - ie), nrm);
  const float A1 = chv + isn * c2;        // * beta_i
  const float Cu = isn * scl * is1;
  const float A2 = Cu * sc;               // * gamma_i * x_i
  const float A3 = Cu * kk;               // * gamma_i * avg_i
  const float A4 = fmaf(Cu * gm0, coef, isn * c2);  // += at channel 0

  float* ob = out + (size_t)wid * 1024;
#pragma unroll
  for (int j = 0; j < 4; ++j) {
    const int sp = 2 * j + par;           // pixel of this lane's j-th quad
    const float a1 = __shfl(A1, sp, 64);
    const float a2 = __shfl(A2, sp, 64);
    const float a3 = __shfl(A3, sp, 64);
    const float a4 = __shfl(A4, sp, 64);
    float4 o4;
    o4.x = fmaf(a1, bt4.x, gm4.x * fmaf(a2, xv[j].x, a3 * av.x));
    o4.y = fmaf(a1, bt4.y, gm4.y * fmaf(a2, xv[j].y, a3 * av.y));
    o4.z = fmaf(a1, bt4.z, gm4.z * fmaf(a2, xv[j].z, a3 * av.z));
    o4.w = fmaf(a1, bt4.w, gm4.w * fmaf(a2, xv[j].w, a3 * av.w));
    if (cl == 0) o4.x += a4;              // channel 0 of this pixel
    *reinterpret_cast<float4*>(ob + j * 256 + 4 * lane) = o4;
  }
}

extern "C" void kernel_launch(void* const* d_in, const int* in_sizes, int n_in,
                              void* d_out, int out_size, void* d_ws,
                              size_t ws_size, hipStream_t stream) {
  const float* x = (const float*)d_in[0];
  const float* gamma = (const float*)d_in[1];
  const float* beta = (const float*)d_in[2];
  float* out = (float*)d_out;
  float* var_part = (float*)d_ws;                      // 512*392 floats
  float* var_final = var_part + (size_t)N_GROUPS * 8;  // 513 floats (last=<b,b>_L)
  float* cache = var_part + 201472;                    // 16B-aligned, ~6.4 MB

  lngn_pass1<<<N_GROUPS / 4, 256, 0, stream>>>(x, gamma, beta, var_part, cache);
  lngn_finalize<<<128, 256, 0, stream>>>(var_part, beta, var_final);
  lngn_pass2<<<N_GROUPS / 4, 256, 0, stream>>>(x, gamma, beta, var_final, cache,
                                               out);
}